// Round 4
// baseline (482.664 us; speedup 1.0000x reference)
//
#include <hip/hip_runtime.h>
#include <math.h>

// SCNCore: hidden = sigmoid((concept@Wci^T)*(x@Win^T) + (concept@Wcs^T)*(h@Wst^T))
//          i,f,o,cc = split(hidden,4); c_t = i*cc + f*c_state; h_t = o*tanh(c_t)
// B=1024, IN=H=1024, C=1000, 4H=4096.
//
// R4 decode (hardware-confirmed): inputs fp32 (bf16 read => NaN, R1/R2),
// OUTPUT fp32 (R3 err 2.97 > 2 == packed-bf16-read-as-fp32 signature).
// Dtype detector kept as a guard; fp32 path expected. hidden staged bf16 in ws.

typedef __bf16 bf16_t;
typedef __bf16 bf16x8 __attribute__((ext_vector_type(8)));
typedef float floatx4 __attribute__((ext_vector_type(4)));

#define THREADS 256
#define BM 128
#define BN 64
#define H4 4096

// ---- dtype detector: 64 u16s of core_input viewed as bf16; fp32 data's low
// half-words are ~uniform random => some bf16-exponent >= 137 (|x|>=2^10).
__global__ void detect_dtype(const unsigned short* __restrict__ p, int* __restrict__ flag) {
  const int lane = threadIdx.x & 63;
  const unsigned short v = p[lane];
  const int e = (v >> 7) & 0xFF;
  const unsigned long long m = __ballot(e >= 137);
  if (lane == 0) *flag = (m != 0ull) ? 1 : 0;
}

// ---- stage ITERS*4096 B of a K-contiguous tile into XOR-swizzled bf16 LDS.
// LDS row = 128 B (64 bf16); chunk slot s of row r holds global chunk s^(r&7).
// Chunks with elemBase+8 > Kelems are zero-filled (K=1000 tail; 1000%8==0).
template<int ITERS>
__device__ __forceinline__ void stage_tile(
    const char* __restrict__ g, int row0, int Kelems, int kBase,
    char* s, int tid, int isF32)
{
#pragma unroll
  for (int it = 0; it < ITERS; ++it) {
    const int flat = it * 4096 + tid * 16;
    const int row  = flat >> 7;
    const int slot = (flat >> 4) & 7;
    const int eb   = kBase + ((slot ^ (row & 7)) << 3);   // element base of chunk
    bf16x8 v;
#pragma unroll
    for (int e = 0; e < 8; ++e) v[e] = (bf16_t)0.f;
    if (eb + 8 <= Kelems) {
      const size_t e0 = (size_t)(row0 + row) * (size_t)Kelems + (size_t)eb;
      if (isF32) {
        const float4 f0 = *(const float4*)(g + e0 * 4);
        const float4 f1 = *(const float4*)(g + e0 * 4 + 16);
        v[0] = (bf16_t)f0.x; v[1] = (bf16_t)f0.y; v[2] = (bf16_t)f0.z; v[3] = (bf16_t)f0.w;
        v[4] = (bf16_t)f1.x; v[5] = (bf16_t)f1.y; v[6] = (bf16_t)f1.z; v[7] = (bf16_t)f1.w;
      } else {
        v = *(const bf16x8*)(g + e0 * 2);
      }
    }
    *(bf16x8*)(s + flat) = v;
  }
}

// ---- MFMA over staged tiles: 2 k-steps of 32; wave tile 32(M) x 64(N)
__device__ __forceinline__ void compute_block(const char* sA, const char* sB,
                                              int w, int l15, int quad,
                                              floatx4 (&acc)[2][4]) {
#pragma unroll
  for (int ks = 0; ks < 2; ++ks) {
    bf16x8 af[2], bfr[4];
#pragma unroll
    for (int mi = 0; mi < 2; ++mi) {
      const int r = w * 32 + mi * 16 + l15;
      const int c = (ks * 4 + quad) ^ (r & 7);        // XOR-unswizzle
      af[mi] = *(const bf16x8*)(sA + r * 128 + c * 16);
    }
#pragma unroll
    for (int ni = 0; ni < 4; ++ni) {
      const int r = ni * 16 + l15;
      const int c = (ks * 4 + quad) ^ (r & 7);
      bfr[ni] = *(const bf16x8*)(sB + r * 128 + c * 16);
    }
#pragma unroll
    for (int mi = 0; mi < 2; ++mi)
#pragma unroll
      for (int ni = 0; ni < 4; ++ni)
        acc[mi][ni] = __builtin_amdgcn_mfma_f32_16x16x32_bf16(af[mi], bfr[ni],
                                                              acc[mi][ni], 0, 0, 0);
  }
}

// acc += A[M0:M0+128, :K] * W[N0:N0+64, :K]^T, both K-contiguous.
__device__ __forceinline__ void gemm_phase(
    const char* __restrict__ gA, int M0,
    const char* __restrict__ gW, int N0, int Kelems,
    char* sA, char* sB, int tid, int isF32, floatx4 (&acc)[2][4])
{
  const int w = tid >> 6, lane = tid & 63, l15 = lane & 15, quad = lane >> 4;
  const int iters = (Kelems + 63) >> 6;   // 16 for K=1024 and K=1000
  for (int i = 0; i < iters; ++i) {
    const int kb = i * 64;
    __syncthreads();                       // prev readers done before overwrite
    stage_tile<4>(gA, M0, Kelems, kb, sA, tid, isF32);
    stage_tile<2>(gW, N0, Kelems, kb, sB, tid, isF32);
    __syncthreads();                       // staged data visible
    compute_block(sA, sB, w, l15, quad, acc);
  }
}

__global__ __launch_bounds__(THREADS)
void scn_gemm(const char* __restrict__ x,   const char* __restrict__ h,
              const char* __restrict__ cpt,
              const char* __restrict__ Win, const char* __restrict__ Wst,
              const char* __restrict__ Wci, const char* __restrict__ Wcs,
              const int* __restrict__ flag, bf16_t* __restrict__ hidden)
{
  __shared__ __align__(16) char sA[BM * 128];  // 16 KiB
  __shared__ __align__(16) char sB[BN * 128];  //  8 KiB
  const int tid = threadIdx.x;
  const int isF32 = *flag;
  const int N0 = blockIdx.x * BN;
  const int M0 = blockIdx.y * BM;

  floatx4 acc0[2][4], acc1[2][4], acc2[2][4];
  const floatx4 z = {0.f, 0.f, 0.f, 0.f};
#pragma unroll
  for (int mi = 0; mi < 2; ++mi)
#pragma unroll
    for (int ni = 0; ni < 4; ++ni) { acc0[mi][ni] = z; acc1[mi][ni] = z; acc2[mi][ni] = z; }

  // xi = x @ Win^T (K=1024)
  gemm_phase(x, M0, Win, N0, 1024, sA, sB, tid, isF32, acc0);
  // gi = concept @ Wci^T (K=1000)
  gemm_phase(cpt, M0, Wci, N0, 1000, sA, sB, tid, isF32, acc1);
  // P = xi * gi (identical C/D fragment layout -> per-register product)
#pragma unroll
  for (int mi = 0; mi < 2; ++mi)
#pragma unroll
    for (int ni = 0; ni < 4; ++ni) { acc0[mi][ni] = acc0[mi][ni] * acc1[mi][ni]; acc1[mi][ni] = z; }
  // hs = h @ Wst^T (K=1024)
  gemm_phase(h, M0, Wst, N0, 1024, sA, sB, tid, isF32, acc1);
  // gs = concept @ Wcs^T (K=1000)
  gemm_phase(cpt, M0, Wcs, N0, 1000, sA, sB, tid, isF32, acc2);

  // hidden = sigmoid(P + hs*gs); C/D layout: row = quad*4 + r, col = l15
  const int w = tid >> 6, lane = tid & 63, l15 = lane & 15, quad = lane >> 4;
#pragma unroll
  for (int mi = 0; mi < 2; ++mi)
#pragma unroll
    for (int ni = 0; ni < 4; ++ni)
#pragma unroll
      for (int r = 0; r < 4; ++r) {
        const float e = acc0[mi][ni][r] + acc1[mi][ni][r] * acc2[mi][ni][r];
        const float s = 1.f / (1.f + __expf(-e));
        const int row = M0 + w * 32 + mi * 16 + quad * 4 + r;
        const int col = N0 + ni * 16 + l15;
        hidden[(size_t)row * H4 + col] = (bf16_t)s;
      }
}

__global__ __launch_bounds__(THREADS)
void scn_combine(const bf16_t* __restrict__ hidden, const char* __restrict__ cs,
                 const int* __restrict__ flag, float* __restrict__ out)
{
  const int isF32 = *flag;
  const int t = blockIdx.x * THREADS + threadIdx.x;   // 0..131071
  const size_t idx = (size_t)t * 8;
  const size_t b = idx >> 10, col = idx & 1023;
  const size_t hb = b * H4 + col;
  const bf16x8 vi = *(const bf16x8*)(hidden + hb);
  const bf16x8 vf = *(const bf16x8*)(hidden + hb + 1024);
  const bf16x8 vo = *(const bf16x8*)(hidden + hb + 2048);
  const bf16x8 vc = *(const bf16x8*)(hidden + hb + 3072);
  float cv[8];
  if (isF32) {
    const float4 a = *(const float4*)(cs + idx * 4);
    const float4 d = *(const float4*)(cs + idx * 4 + 16);
    cv[0] = a.x; cv[1] = a.y; cv[2] = a.z; cv[3] = a.w;
    cv[4] = d.x; cv[5] = d.y; cv[6] = d.z; cv[7] = d.w;
  } else {
    const bf16x8 v = *(const bf16x8*)(cs + idx * 2);
#pragma unroll
    for (int e = 0; e < 8; ++e) cv[e] = (float)v[e];
  }
  float ht[8], ct[8];
#pragma unroll
  for (int e = 0; e < 8; ++e) {
    ct[e] = (float)vi[e] * (float)vc[e] + (float)vf[e] * cv[e];
    ht[e] = (float)vo[e] * tanhf(ct[e]);
  }
  // fp32 outputs: h_t at [0, 1M), c_t at [1M, 2M)
  *(float4*)(out + idx)     = make_float4(ht[0], ht[1], ht[2], ht[3]);
  *(float4*)(out + idx + 4) = make_float4(ht[4], ht[5], ht[6], ht[7]);
  float* outc = out + (1u << 20);
  *(float4*)(outc + idx)     = make_float4(ct[0], ct[1], ct[2], ct[3]);
  *(float4*)(outc + idx + 4) = make_float4(ct[4], ct[5], ct[6], ct[7]);
}

extern "C" void kernel_launch(void* const* d_in, const int* in_sizes, int n_in,
                              void* d_out, int out_size, void* d_ws, size_t ws_size,
                              hipStream_t stream) {
  (void)in_sizes; (void)n_in; (void)out_size; (void)ws_size;
  const char* x   = (const char*)d_in[0];
  const char* h   = (const char*)d_in[1];
  const char* cst = (const char*)d_in[2];
  const char* cpt = (const char*)d_in[3];
  const char* Win = (const char*)d_in[4];
  const char* Wst = (const char*)d_in[5];
  const char* Wci = (const char*)d_in[6];
  const char* Wcs = (const char*)d_in[7];

  int*    flag   = (int*)d_ws;                       // 4 B
  bf16_t* hidden = (bf16_t*)((char*)d_ws + 256);     // 8 MiB @ d_ws+256
  float*  out    = (float*)d_out;

  detect_dtype<<<1, 64, 0, stream>>>((const unsigned short*)d_in[0], flag);
  dim3 grid(H4 / BN, 1024 / BM);                     // 64 x 8 = 512 blocks
  scn_gemm<<<grid, THREADS, 0, stream>>>(x, h, cpt, Win, Wst, Wci, Wcs, flag, hidden);
  scn_combine<<<(1024 * 1024 / 8) / THREADS, THREADS, 0, stream>>>(hidden, cst, flag, out);
}

// Round 5
// 174.694 us; speedup vs baseline: 2.7629x; 2.7629x over previous
//
#include <hip/hip_runtime.h>
#include <math.h>

// SCNCore: hidden = sigmoid((concept@Wci^T)*(x@Win^T) + (concept@Wcs^T)*(h@Wst^T))
//          i,f,o,cc = split(hidden,4); c_t = i*cc + f*c_state; h_t = o*tanh(c_t)
// B=1024, IN=H=1024, C=1000, 4H=4096. Inputs fp32, outputs fp32 (HW-confirmed R4).
//
// R5: (1) fp32->bf16 convert kernels (K padded 1000->1024, zeros) so the GEMM
// is pure bf16 / uniform K; (2) m97-style global_load_lds(16B) staging (zero
// VGPR staging, async); (3) concept phase fused: stage concept tile once, MFMA
// vs both Wci & Wcs. Fallback to R4 path if ws_size < 46 MiB.

typedef __bf16 bf16_t;
typedef __bf16 bf16x8 __attribute__((ext_vector_type(8)));
typedef float floatx4 __attribute__((ext_vector_type(4)));

#define THREADS 256
#define H4 4096

__device__ __forceinline__ void glds16(const void* g, void* l) {
  // async global->LDS: 16 B/lane, LDS dest = wave-uniform base + lane*16
  __builtin_amdgcn_global_load_lds((const __attribute__((address_space(1))) void*)g,
                                   (__attribute__((address_space(3))) void*)l,
                                   16, 0, 0);
}

// ============================ convert kernels ============================
__global__ __launch_bounds__(THREADS)
void conv_unpadded(const float* __restrict__ x, const float* __restrict__ h,
                   const float* __restrict__ Win, const float* __restrict__ Wst,
                   bf16_t* __restrict__ xb, bf16_t* __restrict__ hb,
                   bf16_t* __restrict__ Winb, bf16_t* __restrict__ Wstb)
{
  const int c = blockIdx.x * THREADS + threadIdx.x;  // chunk of 8 elems, 0..1310719
  const float* src; bf16_t* dst; int off;
  if      (c < 131072) { src = x;   dst = xb;   off = c; }
  else if (c < 262144) { src = h;   dst = hb;   off = c - 131072; }
  else if (c < 786432) { src = Win; dst = Winb; off = c - 262144; }
  else                 { src = Wst; dst = Wstb; off = c - 786432; }
  const size_t e0 = (size_t)off * 8;
  const float4 f0 = *(const float4*)(src + e0);
  const float4 f1 = *(const float4*)(src + e0 + 4);
  bf16x8 v;
  v[0] = (bf16_t)f0.x; v[1] = (bf16_t)f0.y; v[2] = (bf16_t)f0.z; v[3] = (bf16_t)f0.w;
  v[4] = (bf16_t)f1.x; v[5] = (bf16_t)f1.y; v[6] = (bf16_t)f1.z; v[7] = (bf16_t)f1.w;
  *(bf16x8*)(dst + e0) = v;
}

__global__ __launch_bounds__(THREADS)
void conv_padded(const float* __restrict__ cpt, const float* __restrict__ Wci,
                 const float* __restrict__ Wcs,
                 bf16_t* __restrict__ cb, bf16_t* __restrict__ Wcib,
                 bf16_t* __restrict__ Wcsb)
{
  // rows: concept 1024, Wci 4096, Wcs 4096 = 9216; K 1000 -> 1024 (chunks 125..127 zero)
  const int rid   = blockIdx.x * 2 + (threadIdx.x >> 7);
  const int chunk = threadIdx.x & 127;
  const float* src; bf16_t* dst; int row;
  if      (rid < 1024) { src = cpt; dst = cb;   row = rid; }
  else if (rid < 5120) { src = Wci; dst = Wcib; row = rid - 1024; }
  else                 { src = Wcs; dst = Wcsb; row = rid - 5120; }
  bf16x8 v;
#pragma unroll
  for (int e = 0; e < 8; ++e) v[e] = (bf16_t)0.f;
  if (chunk < 125) {  // 125*8 = 1000; row*4000 B and chunk*32 B are 16B-aligned
    const size_t s0 = (size_t)row * 1000 + (size_t)chunk * 8;
    const float4 f0 = *(const float4*)(src + s0);
    const float4 f1 = *(const float4*)(src + s0 + 4);
    v[0] = (bf16_t)f0.x; v[1] = (bf16_t)f0.y; v[2] = (bf16_t)f0.z; v[3] = (bf16_t)f0.w;
    v[4] = (bf16_t)f1.x; v[5] = (bf16_t)f1.y; v[6] = (bf16_t)f1.z; v[7] = (bf16_t)f1.w;
  }
  *(bf16x8*)(dst + (size_t)row * 1024 + (size_t)chunk * 8) = v;
}

// ============================ fast GEMM (bf16, glds16) ============================
// LDS row = 128 B (64 bf16, one BK tile); slot s of row r holds global chunk s^(r&7).
__device__ __forceinline__ void stage4(const bf16_t* g, int row0, int kByte,
                                       char* s, int w, int lane) {
#pragma unroll
  for (int it = 0; it < 4; ++it) {
    const int flat = it * 4096 + w * 1024 + lane * 16;
    const int row  = flat >> 7;
    const int slot = (flat >> 4) & 7;
    const int srcb = kByte + ((slot ^ (row & 7)) << 4);
    glds16((const char*)g + (size_t)(row0 + row) * 2048 + srcb, s + it * 4096 + w * 1024);
  }
}
__device__ __forceinline__ void stage2(const bf16_t* g, int row0, int kByte,
                                       char* s, int w, int lane) {
#pragma unroll
  for (int it = 0; it < 2; ++it) {
    const int flat = it * 4096 + w * 1024 + lane * 16;
    const int row  = flat >> 7;
    const int slot = (flat >> 4) & 7;
    const int srcb = kByte + ((slot ^ (row & 7)) << 4);
    glds16((const char*)g + (size_t)(row0 + row) * 2048 + srcb, s + it * 4096 + w * 1024);
  }
}

__device__ __forceinline__ void compute_block(const char* sA, const char* sB,
                                              int w, int l15, int quad,
                                              floatx4 (&acc)[2][4]) {
#pragma unroll
  for (int ks = 0; ks < 2; ++ks) {
    bf16x8 af[2], bfr[4];
#pragma unroll
    for (int mi = 0; mi < 2; ++mi) {
      const int r = w * 32 + mi * 16 + l15;
      const int c = (ks * 4 + quad) ^ (r & 7);
      af[mi] = *(const bf16x8*)(sA + r * 128 + c * 16);
    }
#pragma unroll
    for (int ni = 0; ni < 4; ++ni) {
      const int r = ni * 16 + l15;
      const int c = (ks * 4 + quad) ^ (r & 7);
      bfr[ni] = *(const bf16x8*)(sB + r * 128 + c * 16);
    }
#pragma unroll
    for (int mi = 0; mi < 2; ++mi)
#pragma unroll
      for (int ni = 0; ni < 4; ++ni)
        acc[mi][ni] = __builtin_amdgcn_mfma_f32_16x16x32_bf16(af[mi], bfr[ni],
                                                              acc[mi][ni], 0, 0, 0);
  }
}

__device__ __forceinline__ void compute_block2(const char* sA, const char* sB1,
                                               const char* sB2, int w, int l15, int quad,
                                               floatx4 (&acc1)[2][4], floatx4 (&acc2)[2][4]) {
#pragma unroll
  for (int ks = 0; ks < 2; ++ks) {
    bf16x8 af[2], b1[4], b2[4];
#pragma unroll
    for (int mi = 0; mi < 2; ++mi) {
      const int r = w * 32 + mi * 16 + l15;
      const int c = (ks * 4 + quad) ^ (r & 7);
      af[mi] = *(const bf16x8*)(sA + r * 128 + c * 16);
    }
#pragma unroll
    for (int ni = 0; ni < 4; ++ni) {
      const int r = ni * 16 + l15;
      const int c = (ks * 4 + quad) ^ (r & 7);
      b1[ni] = *(const bf16x8*)(sB1 + r * 128 + c * 16);
      b2[ni] = *(const bf16x8*)(sB2 + r * 128 + c * 16);
    }
#pragma unroll
    for (int mi = 0; mi < 2; ++mi)
#pragma unroll
      for (int ni = 0; ni < 4; ++ni) {
        acc1[mi][ni] = __builtin_amdgcn_mfma_f32_16x16x32_bf16(af[mi], b1[ni],
                                                               acc1[mi][ni], 0, 0, 0);
        acc2[mi][ni] = __builtin_amdgcn_mfma_f32_16x16x32_bf16(af[mi], b2[ni],
                                                               acc2[mi][ni], 0, 0, 0);
      }
  }
}

__global__ __launch_bounds__(THREADS)
void scn_gemm_fast(const bf16_t* __restrict__ xb,   const bf16_t* __restrict__ hb,
                   const bf16_t* __restrict__ cb,
                   const bf16_t* __restrict__ Winb, const bf16_t* __restrict__ Wstb,
                   const bf16_t* __restrict__ Wcib, const bf16_t* __restrict__ Wcsb,
                   bf16_t* __restrict__ hidden)
{
  __shared__ __align__(16) char sA [128 * 128];  // 16 KiB
  __shared__ __align__(16) char sB1[ 64 * 128];  //  8 KiB
  __shared__ __align__(16) char sB2[ 64 * 128];  //  8 KiB
  const int tid = threadIdx.x;
  const int w = tid >> 6, lane = tid & 63, l15 = lane & 15, quad = lane >> 4;
  const int N0 = blockIdx.x * 64, M0 = blockIdx.y * 128;

  floatx4 acc0[2][4], acc1[2][4], acc2[2][4];
  const floatx4 z = {0.f, 0.f, 0.f, 0.f};
#pragma unroll
  for (int mi = 0; mi < 2; ++mi)
#pragma unroll
    for (int ni = 0; ni < 4; ++ni) { acc0[mi][ni] = z; acc1[mi][ni] = z; acc2[mi][ni] = z; }

  // phase 1: xi = x @ Win^T -> acc0
  for (int i = 0; i < 16; ++i) {
    const int kb = i * 128;
    __syncthreads();
    stage4(xb, M0, kb, sA, w, lane);
    stage2(Winb, N0, kb, sB1, w, lane);
    __syncthreads();
    compute_block(sA, sB1, w, l15, quad, acc0);
  }
  // phase 2 (fused): gi -> acc1, gs -> acc2 (concept tile staged once)
  for (int i = 0; i < 16; ++i) {
    const int kb = i * 128;
    __syncthreads();
    stage4(cb, M0, kb, sA, w, lane);
    stage2(Wcib, N0, kb, sB1, w, lane);
    stage2(Wcsb, N0, kb, sB2, w, lane);
    __syncthreads();
    compute_block2(sA, sB1, sB2, w, l15, quad, acc1, acc2);
  }
  // P = xi * gi (same fragment layout); recycle acc1 for hs
#pragma unroll
  for (int mi = 0; mi < 2; ++mi)
#pragma unroll
    for (int ni = 0; ni < 4; ++ni) { acc0[mi][ni] = acc0[mi][ni] * acc1[mi][ni]; acc1[mi][ni] = z; }
  // phase 3: hs = h @ Wst^T -> acc1
  for (int i = 0; i < 16; ++i) {
    const int kb = i * 128;
    __syncthreads();
    stage4(hb, M0, kb, sA, w, lane);
    stage2(Wstb, N0, kb, sB1, w, lane);
    __syncthreads();
    compute_block(sA, sB1, w, l15, quad, acc1);
  }

  // hidden = sigmoid(P + hs*gs); C/D layout: row = quad*4 + r, col = l15
#pragma unroll
  for (int mi = 0; mi < 2; ++mi)
#pragma unroll
    for (int ni = 0; ni < 4; ++ni)
#pragma unroll
      for (int r = 0; r < 4; ++r) {
        const float e = acc0[mi][ni][r] + acc1[mi][ni][r] * acc2[mi][ni][r];
        const float s = 1.f / (1.f + __expf(-e));
        const int row = M0 + w * 32 + mi * 16 + quad * 4 + r;
        const int col = N0 + ni * 16 + l15;
        hidden[(size_t)row * H4 + col] = (bf16_t)s;
      }
}

// ============================ legacy path (R4, fallback) ============================
template<int ITERS>
__device__ __forceinline__ void stage_tile_f32(const char* __restrict__ g, int row0,
                                               int Kelems, int kBase, char* s, int tid)
{
#pragma unroll
  for (int it = 0; it < ITERS; ++it) {
    const int flat = it * 4096 + tid * 16;
    const int row  = flat >> 7;
    const int slot = (flat >> 4) & 7;
    const int eb   = kBase + ((slot ^ (row & 7)) << 3);
    bf16x8 v;
#pragma unroll
    for (int e = 0; e < 8; ++e) v[e] = (bf16_t)0.f;
    if (eb + 8 <= Kelems) {
      const size_t e0 = (size_t)(row0 + row) * (size_t)Kelems + (size_t)eb;
      const float4 f0 = *(const float4*)(g + e0 * 4);
      const float4 f1 = *(const float4*)(g + e0 * 4 + 16);
      v[0] = (bf16_t)f0.x; v[1] = (bf16_t)f0.y; v[2] = (bf16_t)f0.z; v[3] = (bf16_t)f0.w;
      v[4] = (bf16_t)f1.x; v[5] = (bf16_t)f1.y; v[6] = (bf16_t)f1.z; v[7] = (bf16_t)f1.w;
    }
    *(bf16x8*)(s + flat) = v;
  }
}

__device__ __forceinline__ void gemm_phase_legacy(
    const char* __restrict__ gA, int M0, const char* __restrict__ gW, int N0,
    int Kelems, char* sA, char* sB, int tid, floatx4 (&acc)[2][4])
{
  const int w = tid >> 6, lane = tid & 63, l15 = lane & 15, quad = lane >> 4;
  const int iters = (Kelems + 63) >> 6;
  for (int i = 0; i < iters; ++i) {
    const int kb = i * 64;
    __syncthreads();
    stage_tile_f32<4>(gA, M0, Kelems, kb, sA, tid);
    stage_tile_f32<2>(gW, N0, Kelems, kb, sB, tid);
    __syncthreads();
    compute_block(sA, sB, w, l15, quad, acc);
  }
}

__global__ __launch_bounds__(THREADS)
void scn_gemm_legacy(const char* __restrict__ x, const char* __restrict__ h,
                     const char* __restrict__ cpt,
                     const char* __restrict__ Win, const char* __restrict__ Wst,
                     const char* __restrict__ Wci, const char* __restrict__ Wcs,
                     bf16_t* __restrict__ hidden)
{
  __shared__ __align__(16) char sA[128 * 128];
  __shared__ __align__(16) char sB[64 * 128];
  const int tid = threadIdx.x;
  const int N0 = blockIdx.x * 64, M0 = blockIdx.y * 128;
  floatx4 acc0[2][4], acc1[2][4], acc2[2][4];
  const floatx4 z = {0.f, 0.f, 0.f, 0.f};
#pragma unroll
  for (int mi = 0; mi < 2; ++mi)
#pragma unroll
    for (int ni = 0; ni < 4; ++ni) { acc0[mi][ni] = z; acc1[mi][ni] = z; acc2[mi][ni] = z; }
  gemm_phase_legacy(x, M0, Win, N0, 1024, sA, sB, tid, acc0);
  gemm_phase_legacy(cpt, M0, Wci, N0, 1000, sA, sB, tid, acc1);
#pragma unroll
  for (int mi = 0; mi < 2; ++mi)
#pragma unroll
    for (int ni = 0; ni < 4; ++ni) { acc0[mi][ni] = acc0[mi][ni] * acc1[mi][ni]; acc1[mi][ni] = z; }
  gemm_phase_legacy(h, M0, Wst, N0, 1024, sA, sB, tid, acc1);
  gemm_phase_legacy(cpt, M0, Wcs, N0, 1000, sA, sB, tid, acc2);
  const int w = tid >> 6, lane = tid & 63, l15 = lane & 15, quad = lane >> 4;
#pragma unroll
  for (int mi = 0; mi < 2; ++mi)
#pragma unroll
    for (int ni = 0; ni < 4; ++ni)
#pragma unroll
      for (int r = 0; r < 4; ++r) {
        const float e = acc0[mi][ni][r] + acc1[mi][ni][r] * acc2[mi][ni][r];
        const float s = 1.f / (1.f + __expf(-e));
        const int row = M0 + w * 32 + mi * 16 + quad * 4 + r;
        const int col = N0 + ni * 16 + l15;
        hidden[(size_t)row * H4 + col] = (bf16_t)s;
      }
}

// ============================ combine ============================
__global__ __launch_bounds__(THREADS)
void scn_combine(const bf16_t* __restrict__ hidden, const float* __restrict__ cs,
                 float* __restrict__ out)
{
  const int t = blockIdx.x * THREADS + threadIdx.x;   // 0..131071
  const size_t idx = (size_t)t * 8;
  const size_t b = idx >> 10, col = idx & 1023;
  const size_t hb = b * H4 + col;
  const bf16x8 vi = *(const bf16x8*)(hidden + hb);
  const bf16x8 vf = *(const bf16x8*)(hidden + hb + 1024);
  const bf16x8 vo = *(const bf16x8*)(hidden + hb + 2048);
  const bf16x8 vc = *(const bf16x8*)(hidden + hb + 3072);
  const float4 a = *(const float4*)(cs + idx);
  const float4 d = *(const float4*)(cs + idx + 4);
  const float cv[8] = {a.x, a.y, a.z, a.w, d.x, d.y, d.z, d.w};
  float ht[8], ct[8];
#pragma unroll
  for (int e = 0; e < 8; ++e) {
    ct[e] = (float)vi[e] * (float)vc[e] + (float)vf[e] * cv[e];
    ht[e] = (float)vo[e] * tanhf(ct[e]);
  }
  *(float4*)(out + idx)     = make_float4(ht[0], ht[1], ht[2], ht[3]);
  *(float4*)(out + idx + 4) = make_float4(ht[4], ht[5], ht[6], ht[7]);
  float* outc = out + (1u << 20);
  *(float4*)(outc + idx)     = make_float4(ct[0], ct[1], ct[2], ct[3]);
  *(float4*)(outc + idx + 4) = make_float4(ct[4], ct[5], ct[6], ct[7]);
}

extern "C" void kernel_launch(void* const* d_in, const int* in_sizes, int n_in,
                              void* d_out, int out_size, void* d_ws, size_t ws_size,
                              hipStream_t stream) {
  (void)in_sizes; (void)n_in; (void)out_size;
  const float* x   = (const float*)d_in[0];
  const float* h   = (const float*)d_in[1];
  const float* cst = (const float*)d_in[2];
  const float* cpt = (const float*)d_in[3];
  const float* Win = (const float*)d_in[4];
  const float* Wst = (const float*)d_in[5];
  const float* Wci = (const float*)d_in[6];
  const float* Wcs = (const float*)d_in[7];
  float* out = (float*)d_out;
  const size_t MB = 1u << 20;
  dim3 grid(H4 / 64, 1024 / 128);    // 64 x 8 = 512 blocks

  if (ws_size >= 46 * MB) {
    char* ws = (char*)d_ws;
    bf16_t* xb    = (bf16_t*)(ws);            // 2 MiB
    bf16_t* hbuf  = (bf16_t*)(ws + 2 * MB);   // 2 MiB
    bf16_t* cb    = (bf16_t*)(ws + 4 * MB);   // 2 MiB (K padded)
    bf16_t* Winb  = (bf16_t*)(ws + 6 * MB);   // 8 MiB
    bf16_t* Wstb  = (bf16_t*)(ws + 14 * MB);  // 8 MiB
    bf16_t* Wcib  = (bf16_t*)(ws + 22 * MB);  // 8 MiB (K padded)
    bf16_t* Wcsb  = (bf16_t*)(ws + 30 * MB);  // 8 MiB (K padded)
    bf16_t* hidden= (bf16_t*)(ws + 38 * MB);  // 8 MiB
    conv_unpadded<<<5120, THREADS, 0, stream>>>(x, h, Win, Wst, xb, hbuf, Winb, Wstb);
    conv_padded<<<4608, THREADS, 0, stream>>>(cpt, Wci, Wcs, cb, Wcib, Wcsb);
    scn_gemm_fast<<<grid, THREADS, 0, stream>>>(xb, hbuf, cb, Winb, Wstb, Wcib, Wcsb, hidden);
    scn_combine<<<(1024 * 1024 / 8) / THREADS, THREADS, 0, stream>>>(hidden, cst, out);
  } else {
    bf16_t* hidden = (bf16_t*)((char*)d_ws + 256);
    scn_gemm_legacy<<<grid, THREADS, 0, stream>>>(
        (const char*)x, (const char*)h, (const char*)cpt,
        (const char*)Win, (const char*)Wst, (const char*)Wci, (const char*)Wcs, hidden);
    scn_combine<<<(1024 * 1024 / 8) / THREADS, THREADS, 0, stream>>>(hidden, cst, out);
  }
}